// Round 1
// baseline (166.704 us; speedup 1.0000x reference)
//
#include <hip/hip_runtime.h>
#include <hip/hip_bf16.h>

typedef __attribute__((ext_vector_type(8))) short short8;
typedef __attribute__((ext_vector_type(4))) float f32x4;

// ---- geometry ----
// x,y: (1,32,36,48,48) f32.  conv 3x3x3 SAME -> unfold P=9 -> t (32,1024,81)
// res_trans: a = LeakyReLU(t @ (W2@W1)^T)   (81x81 collapsed matrix M)
// att: (1/81) * a @ b^T per channel -> (1,32,1024,1024) f32
// K padded 81 -> 96 everywhere.

static __device__ __forceinline__ unsigned short f2bf(float f) {
    unsigned int u = __float_as_uint(f);
    unsigned int r = (u + 0x7fffu + ((u >> 16) & 1u)) >> 16;
    return (unsigned short)r;
}

// ---------------- prep: M = W2@W1 (bf16, 96x96 padded) + weight rearrange ----
// Wbf layout: [img][tap(27)][co(32)][ci(40 padded)] bf16
__global__ void prep_kernel(const float* __restrict__ W1, const float* __restrict__ W2,
                            const float* __restrict__ Wx, const float* __restrict__ Wy,
                            unsigned short* __restrict__ Mo, unsigned short* __restrict__ Wbf) {
    int gid = blockIdx.x * 256 + threadIdx.x;
    if (blockIdx.x < 36) {                       // 36*256 = 9216 = 96*96
        int o = gid / 96, p = gid % 96;
        float v = 0.f;
        if (o < 81 && p < 81) {
            for (int k = 0; k < 162; ++k) v += W2[o*162 + k] * W1[k*81 + p];
        }
        Mo[o*96 + p] = f2bf(v);
    } else {
        int e = gid - 36*256;                    // 2*27*32*40 = 69120 = 270*256
        if (e < 2*27*32*40) {
            int ci  = e % 40;
            int co  = (e / 40) % 32;
            int tap = (e / (40*32)) % 27;
            int img = e / (40*32*27);
            const float* src = img ? Wy : Wx;
            float v = (ci < 32) ? src[co*864 + ci*27 + tap] : 0.f;
            Wbf[e] = f2bf(v);
        }
    }
}

// ---------------- conv (implicit GEMM, 27 taps x 32-channel K-steps) ---------
// block: one (img, d0, 4 h-rows); wave = one h-row, 3 w-tiles of 16, 2 co-tiles
__global__ __launch_bounds__(256) void conv_kernel(
    const float* __restrict__ x, const float* __restrict__ y,
    const float* __restrict__ bx, const float* __restrict__ by,
    const unsigned short* __restrict__ Wbf, unsigned short* __restrict__ tbuf) {
    __shared__ __align__(16) unsigned short slab[3*6*50*40];  // 72000 B
    int b = blockIdx.x;
    int img = b / 432; int rr = b % 432;
    int d0 = rr / 12; int h0 = (rr % 12) * 4;
    const float* xin  = img ? y  : x;
    const float* bias = img ? by : bx;
    int tid = threadIdx.x;

    // stage x slab -> bf16 LDS, ci innermost, zero halo (d,h OOB and w pads)
    for (int i = 0; i < 113; ++i) {
        int idx = tid + 256*i;
        if (idx < 28800) {                 // 3*6*32*50
            int ww = idx % 50;
            int ci = (idx / 50) % 32;
            int hh = (idx / 1600) % 6;
            int kd = idx / 9600;
            int dd = d0 + kd - 1, hg = h0 + hh - 1, wg = ww - 1;
            float v = 0.f;
            if (dd >= 0 && dd < 36 && hg >= 0 && hg < 48 && wg >= 0 && wg < 48)
                v = xin[((ci*36 + dd)*48 + hg)*48 + wg];
            slab[((kd*6 + hh)*50 + ww)*40 + ci] = f2bf(v);
        }
    }
    __syncthreads();

    int wv = tid >> 6, lane = tid & 63;
    int r16 = lane & 15, g4 = lane >> 4;
    f32x4 acc[2][3];
    #pragma unroll
    for (int i = 0; i < 2; ++i)
        #pragma unroll
        for (int j = 0; j < 3; ++j) acc[i][j] = (f32x4){0.f, 0.f, 0.f, 0.f};

    const unsigned short* Wimg = Wbf + img*(27*32*40);
    for (int kd = 0; kd < 3; ++kd)
    for (int kh = 0; kh < 3; ++kh) {
        const unsigned short* srow = &slab[((kd*6 + wv + kh)*50)*40];
        #pragma unroll
        for (int kw = 0; kw < 3; ++kw) {
            int tap = (kd*3 + kh)*3 + kw;
            short8 a0 = *reinterpret_cast<const short8*>(Wimg + (tap*32 +      r16)*40 + 8*g4);
            short8 a1 = *reinterpret_cast<const short8*>(Wimg + (tap*32 + 16 + r16)*40 + 8*g4);
            #pragma unroll
            for (int wt = 0; wt < 3; ++wt) {
                short8 bfr = *reinterpret_cast<const short8*>(srow + (wt*16 + r16 + kw)*40 + 8*g4);
                acc[0][wt] = __builtin_amdgcn_mfma_f32_16x16x32_bf16(a0, bfr, acc[0][wt], 0, 0, 0);
                acc[1][wt] = __builtin_amdgcn_mfma_f32_16x16x32_bf16(a1, bfr, acc[1][wt], 0, 0, 0);
            }
        }
    }

    // epilogue: + bias, write directly in unfolded layout (C,1024,96) bf16
    int h = h0 + wv;
    int l_hi = (d0/9)*256, p_hi = (d0%9)*9;
    unsigned short* tb = tbuf + img*(32*1024*96);
    #pragma unroll
    for (int ct = 0; ct < 2; ++ct)
    #pragma unroll
    for (int wt = 0; wt < 3; ++wt)
    #pragma unroll
    for (int r = 0; r < 4; ++r) {
        int co = ct*16 + g4*4 + r;
        int w  = wt*16 + r16;
        float v = acc[ct][wt][r] + bias[co];
        int hw = h*48 + w;
        int l = l_hi + hw/9, p = p_hi + hw%9;
        tb[(co*1024 + l)*96 + p] = f2bf(v);
    }
}

// ---------------- res_trans: a = LeakyReLU(t @ M^T), per (img,c) -------------
__global__ __launch_bounds__(256) void rt_kernel(const unsigned short* __restrict__ tbuf,
                                                 const unsigned short* __restrict__ Mo,
                                                 unsigned short* __restrict__ ab) {
    int b = blockIdx.x;
    int img = b >> 7, c = (b >> 2) & 31, mc = b & 3;
    int tid = threadIdx.x, wv = tid >> 6, lane = tid & 63;
    int r16 = lane & 15, g4 = lane >> 4;

    short8 Bf[3][6];
    #pragma unroll
    for (int ks = 0; ks < 3; ++ks)
        #pragma unroll
        for (int n = 0; n < 6; ++n)
            Bf[ks][n] = *reinterpret_cast<const short8*>(Mo + (n*16 + r16)*96 + ks*32 + 8*g4);

    const unsigned short* tc = tbuf + (img*32 + c)*(1024*96);
    unsigned short*       oc = ab   + (img*32 + c)*(1024*96);
    for (int q = 0; q < 4; ++q) {
        int rowb = (mc*16 + wv*4 + q) * 16;
        f32x4 acc[6];
        #pragma unroll
        for (int n = 0; n < 6; ++n) acc[n] = (f32x4){0.f, 0.f, 0.f, 0.f};
        #pragma unroll
        for (int ks = 0; ks < 3; ++ks) {
            short8 Af = *reinterpret_cast<const short8*>(tc + (rowb + r16)*96 + ks*32 + 8*g4);
            #pragma unroll
            for (int n = 0; n < 6; ++n)
                acc[n] = __builtin_amdgcn_mfma_f32_16x16x32_bf16(Af, Bf[ks][n], acc[n], 0, 0, 0);
        }
        #pragma unroll
        for (int n = 0; n < 6; ++n)
            #pragma unroll
            for (int r = 0; r < 4; ++r) {
                int row = rowb + g4*4 + r;
                float v = acc[n][r];
                v = v > 0.f ? v : 0.2f*v;
                oc[row*96 + n*16 + r16] = f2bf(v);
            }
    }
}

// ---------------- att: out = (1/81) a @ b^T per channel ----------------------
// block: (c, 128x128 tile); wave: 32 rows x 128 cols
__global__ __launch_bounds__(256) void att_kernel(const unsigned short* __restrict__ ab,
                                                  float* __restrict__ out) {
    int b = blockIdx.x;
    int c = b >> 6, ty = (b >> 3) & 7, tx = b & 7;
    int tid = threadIdx.x, wv = tid >> 6, lane = tid & 63;
    int r16 = lane & 15, g4 = lane >> 4;
    const unsigned short* arow = ab + c*(1024*96);
    const unsigned short* brow = ab + (32 + c)*(1024*96);
    int rb = ty*128 + wv*32;
    int cb = tx*128;
    f32x4 acc[2][8];
    #pragma unroll
    for (int m = 0; m < 2; ++m)
        #pragma unroll
        for (int n = 0; n < 8; ++n) acc[m][n] = (f32x4){0.f, 0.f, 0.f, 0.f};

    #pragma unroll
    for (int ks = 0; ks < 3; ++ks) {
        short8 A0 = *reinterpret_cast<const short8*>(arow + (rb +      r16)*96 + ks*32 + 8*g4);
        short8 A1 = *reinterpret_cast<const short8*>(arow + (rb + 16 + r16)*96 + ks*32 + 8*g4);
        #pragma unroll
        for (int n = 0; n < 8; ++n) {
            short8 Bf = *reinterpret_cast<const short8*>(brow + (cb + n*16 + r16)*96 + ks*32 + 8*g4);
            acc[0][n] = __builtin_amdgcn_mfma_f32_16x16x32_bf16(A0, Bf, acc[0][n], 0, 0, 0);
            acc[1][n] = __builtin_amdgcn_mfma_f32_16x16x32_bf16(A1, Bf, acc[1][n], 0, 0, 0);
        }
    }
    const float s = 1.f / 81.f;
    #pragma unroll
    for (int mt = 0; mt < 2; ++mt)
        #pragma unroll
        for (int n = 0; n < 8; ++n)
            #pragma unroll
            for (int r = 0; r < 4; ++r) {
                int row = rb + mt*16 + g4*4 + r;
                int col = cb + n*16 + r16;
                out[(c*1024 + row)*1024 + col] = acc[mt][n][r] * s;
            }
}

extern "C" void kernel_launch(void* const* d_in, const int* in_sizes, int n_in,
                              void* d_out, int out_size, void* d_ws, size_t ws_size,
                              hipStream_t stream) {
    const float* x  = (const float*)d_in[0];
    const float* y  = (const float*)d_in[1];
    const float* Wx = (const float*)d_in[2];
    const float* bx = (const float*)d_in[3];
    const float* Wy = (const float*)d_in[4];
    const float* by = (const float*)d_in[5];
    const float* W1 = (const float*)d_in[6];
    const float* W2 = (const float*)d_in[7];
    (void)in_sizes; (void)n_in; (void)out_size; (void)ws_size;

    char* ws = (char*)d_ws;
    unsigned short* Mo   = (unsigned short*)(ws);                       // 18432 B
    unsigned short* Wbf  = (unsigned short*)(ws + 32768);               // 138240 B
    unsigned short* tbuf = (unsigned short*)(ws + 196608);              // 12582912 B
    unsigned short* abuf = (unsigned short*)(ws + 196608 + 12582912);   // 12582912 B
    float* out = (float*)d_out;

    prep_kernel<<<306, 256, 0, stream>>>(W1, W2, Wx, Wy, Mo, Wbf);
    hipMemsetAsync(tbuf, 0, 12582912, stream);   // zero K-pad columns of t
    conv_kernel<<<864, 256, 0, stream>>>(x, y, bx, by, Wbf, tbuf);
    rt_kernel<<<256, 256, 0, stream>>>(tbuf, Mo, abuf);
    att_kernel<<<2048, 256, 0, stream>>>(abuf, out);
}

// Round 2
// 120.233 us; speedup vs baseline: 1.3865x; 1.3865x over previous
//
#include <hip/hip_runtime.h>
#include <hip/hip_bf16.h>

typedef __attribute__((ext_vector_type(8))) short short8;
typedef __attribute__((ext_vector_type(4))) float f32x4;

// ---- geometry ----
// x,y: (1,32,36,48,48) f32.  conv 3x3x3 SAME -> unfold P=9 -> t (32,1024,81)
// res_trans: a = LeakyReLU(t @ (W2@W1)^T)   (81x81 collapsed matrix M)
// att: (1/81) * a @ b^T per channel -> (1,32,1024,1024) f32
// K padded 81 -> 96 in t/a/b buffers.
//
// conv strategy: pre-transpose x,y into zero-padded ci-innermost bf16 layout
// xt[img][38][50][50][32]; conv then needs NO LDS -- every MFMA B fragment is
// a fully-coalesced contiguous 1KB global load (L1/L2 resident).

static __device__ __forceinline__ unsigned short f2bf(float f) {
    unsigned int u = __float_as_uint(f);
    unsigned int r = (u + 0x7fffu + ((u >> 16) & 1u)) >> 16;
    return (unsigned short)r;
}

// ---------------- prep: M = W2@W1 (bf16, 96x96 padded) + weight rearrange ----
// Wbf layout: [img][tap(27)][co(32)][ci(32)] bf16
__global__ void prep_kernel(const float* __restrict__ W1, const float* __restrict__ W2,
                            const float* __restrict__ Wx, const float* __restrict__ Wy,
                            unsigned short* __restrict__ Mo, unsigned short* __restrict__ Wbf) {
    int gid = blockIdx.x * 256 + threadIdx.x;
    if (blockIdx.x < 36) {                       // 36*256 = 9216 = 96*96
        int o = gid / 96, p = gid % 96;
        float v = 0.f;
        if (o < 81 && p < 81) {
            for (int k = 0; k < 162; ++k) v += W2[o*162 + k] * W1[k*81 + p];
        }
        Mo[o*96 + p] = f2bf(v);
    } else {
        int e = gid - 36*256;                    // 2*27*32*32 = 55296 = 216*256
        if (e < 2*27*32*32) {
            int ci  = e % 32;
            int co  = (e / 32) % 32;
            int tap = (e / 1024) % 27;
            int img = e / 27648;
            const float* src = img ? Wy : Wx;
            Wbf[e] = f2bf(src[co*864 + ci*27 + tap]);
        }
    }
}

// ---------------- transpose+pad: x (32,36,48,48) f32 -> xt (38,50,50,32) bf16
__global__ __launch_bounds__(256) void tx_kernel(const float* __restrict__ x,
                                                 const float* __restrict__ y,
                                                 unsigned short* __restrict__ xt) {
    int b = blockIdx.x;                  // img*1728 + d*48 + h
    int img = b / 1728; int r = b % 1728;
    int d = r / 48, h = r % 48;
    const float* src = img ? y : x;
    unsigned short* dst = xt + img*(38*50*50*32) + (((d+1)*50 + (h+1))*50 + 1)*32;
    for (int e = threadIdx.x; e < 1536; e += 256) {
        int w = e >> 5, ci = e & 31;
        dst[w*32 + ci] = f2bf(src[((ci*36 + d)*48 + h)*48 + w]);
    }
}

// ---------------- conv (implicit GEMM, no LDS) -------------------------------
// block: one (img, d0, 4 h-rows); wave = one h-row, 3 w-tiles of 16, 2 co-tiles
__global__ __launch_bounds__(256) void conv_kernel(
    const unsigned short* __restrict__ xt,
    const float* __restrict__ bx, const float* __restrict__ by,
    const unsigned short* __restrict__ Wbf, unsigned short* __restrict__ tbuf) {
    int b = blockIdx.x;
    int img = b / 432; int rr = b % 432;
    int d0 = rr / 12; int h0 = (rr % 12) * 4;
    int tid = threadIdx.x, wv = tid >> 6, lane = tid & 63;
    int r16 = lane & 15, g4 = lane >> 4;
    const unsigned short* Ximg = xt + img*(38*50*50*32);
    const unsigned short* Wimg = Wbf + img*(27*32*32);
    const float* bias = img ? by : bx;

    f32x4 acc[2][3];
    #pragma unroll
    for (int i = 0; i < 2; ++i)
        #pragma unroll
        for (int j = 0; j < 3; ++j) acc[i][j] = (f32x4){0.f, 0.f, 0.f, 0.f};

    int hbase = h0 + wv;
    #pragma unroll
    for (int kd = 0; kd < 3; ++kd)
    #pragma unroll
    for (int kh = 0; kh < 3; ++kh) {
        const unsigned short* xrow = Ximg + ((d0 + kd)*50 + (hbase + kh))*50*32;
        #pragma unroll
        for (int kw = 0; kw < 3; ++kw) {
            int tap = (kd*3 + kh)*3 + kw;
            short8 a0 = *reinterpret_cast<const short8*>(Wimg + (tap*32 +      r16)*32 + 8*g4);
            short8 a1 = *reinterpret_cast<const short8*>(Wimg + (tap*32 + 16 + r16)*32 + 8*g4);
            #pragma unroll
            for (int wt = 0; wt < 3; ++wt) {
                short8 bfr = *reinterpret_cast<const short8*>(xrow + (wt*16 + r16 + kw)*32 + 8*g4);
                acc[0][wt] = __builtin_amdgcn_mfma_f32_16x16x32_bf16(a0, bfr, acc[0][wt], 0, 0, 0);
                acc[1][wt] = __builtin_amdgcn_mfma_f32_16x16x32_bf16(a1, bfr, acc[1][wt], 0, 0, 0);
            }
        }
    }

    // epilogue: + bias, write directly in unfolded layout (C,1024,96) bf16
    int h = hbase;
    int l_hi = (d0/9)*256, p_hi = (d0%9)*9;
    unsigned short* tb = tbuf + img*(32*1024*96);
    #pragma unroll
    for (int ct = 0; ct < 2; ++ct)
    #pragma unroll
    for (int wt = 0; wt < 3; ++wt)
    #pragma unroll
    for (int r = 0; r < 4; ++r) {
        int co = ct*16 + g4*4 + r;
        int w  = wt*16 + r16;
        float v = acc[ct][wt][r] + bias[co];
        int hw = h*48 + w;
        int l = l_hi + hw/9, p = p_hi + hw%9;
        tb[(co*1024 + l)*96 + p] = f2bf(v);
    }
}

// ---------------- res_trans: a = LeakyReLU(t @ M^T), per (img,c) -------------
__global__ __launch_bounds__(256) void rt_kernel(const unsigned short* __restrict__ tbuf,
                                                 const unsigned short* __restrict__ Mo,
                                                 unsigned short* __restrict__ ab) {
    int b = blockIdx.x;
    int img = b >> 7, c = (b >> 2) & 31, mc = b & 3;
    int tid = threadIdx.x, wv = tid >> 6, lane = tid & 63;
    int r16 = lane & 15, g4 = lane >> 4;

    short8 Bf[3][6];
    #pragma unroll
    for (int ks = 0; ks < 3; ++ks)
        #pragma unroll
        for (int n = 0; n < 6; ++n)
            Bf[ks][n] = *reinterpret_cast<const short8*>(Mo + (n*16 + r16)*96 + ks*32 + 8*g4);

    const unsigned short* tc = tbuf + (img*32 + c)*(1024*96);
    unsigned short*       oc = ab   + (img*32 + c)*(1024*96);
    for (int q = 0; q < 4; ++q) {
        int rowb = (mc*16 + wv*4 + q) * 16;
        f32x4 acc[6];
        #pragma unroll
        for (int n = 0; n < 6; ++n) acc[n] = (f32x4){0.f, 0.f, 0.f, 0.f};
        #pragma unroll
        for (int ks = 0; ks < 3; ++ks) {
            short8 Af = *reinterpret_cast<const short8*>(tc + (rowb + r16)*96 + ks*32 + 8*g4);
            #pragma unroll
            for (int n = 0; n < 6; ++n)
                acc[n] = __builtin_amdgcn_mfma_f32_16x16x32_bf16(Af, Bf[ks][n], acc[n], 0, 0, 0);
        }
        #pragma unroll
        for (int n = 0; n < 6; ++n)
            #pragma unroll
            for (int r = 0; r < 4; ++r) {
                int row = rowb + g4*4 + r;
                float v = acc[n][r];
                v = v > 0.f ? v : 0.2f*v;
                oc[row*96 + n*16 + r16] = f2bf(v);
            }
    }
}

// ---------------- att: out = (1/81) a @ b^T per channel ----------------------
__global__ __launch_bounds__(256) void att_kernel(const unsigned short* __restrict__ ab,
                                                  float* __restrict__ out) {
    int b = blockIdx.x;
    int c = b >> 6, ty = (b >> 3) & 7, tx = b & 7;
    int tid = threadIdx.x, wv = tid >> 6, lane = tid & 63;
    int r16 = lane & 15, g4 = lane >> 4;
    const unsigned short* arow = ab + c*(1024*96);
    const unsigned short* brow = ab + (32 + c)*(1024*96);
    int rb = ty*128 + wv*32;
    int cb = tx*128;
    f32x4 acc[2][8];
    #pragma unroll
    for (int m = 0; m < 2; ++m)
        #pragma unroll
        for (int n = 0; n < 8; ++n) acc[m][n] = (f32x4){0.f, 0.f, 0.f, 0.f};

    #pragma unroll
    for (int ks = 0; ks < 3; ++ks) {
        short8 A0 = *reinterpret_cast<const short8*>(arow + (rb +      r16)*96 + ks*32 + 8*g4);
        short8 A1 = *reinterpret_cast<const short8*>(arow + (rb + 16 + r16)*96 + ks*32 + 8*g4);
        #pragma unroll
        for (int n = 0; n < 8; ++n) {
            short8 Bf = *reinterpret_cast<const short8*>(brow + (cb + n*16 + r16)*96 + ks*32 + 8*g4);
            acc[0][n] = __builtin_amdgcn_mfma_f32_16x16x32_bf16(A0, Bf, acc[0][n], 0, 0, 0);
            acc[1][n] = __builtin_amdgcn_mfma_f32_16x16x32_bf16(A1, Bf, acc[1][n], 0, 0, 0);
        }
    }
    const float s = 1.f / 81.f;
    #pragma unroll
    for (int mt = 0; mt < 2; ++mt)
        #pragma unroll
        for (int n = 0; n < 8; ++n)
            #pragma unroll
            for (int r = 0; r < 4; ++r) {
                int row = rb + mt*16 + g4*4 + r;
                int col = cb + n*16 + r16;
                out[(c*1024 + row)*1024 + col] = acc[mt][n][r] * s;
            }
}

extern "C" void kernel_launch(void* const* d_in, const int* in_sizes, int n_in,
                              void* d_out, int out_size, void* d_ws, size_t ws_size,
                              hipStream_t stream) {
    const float* x  = (const float*)d_in[0];
    const float* y  = (const float*)d_in[1];
    const float* Wx = (const float*)d_in[2];
    const float* bx = (const float*)d_in[3];
    const float* Wy = (const float*)d_in[4];
    const float* by = (const float*)d_in[5];
    const float* W1 = (const float*)d_in[6];
    const float* W2 = (const float*)d_in[7];
    (void)in_sizes; (void)n_in; (void)out_size; (void)ws_size;

    // workspace plan (total 25.30 MB, < round-1-proven 25.36 MB):
    //  [0, 12582912)            xt (12.16 MB, dead after conv) then abuf (12.58 MB)
    //  [12582912, 25165824)     tbuf (12.58 MB)
    //  [25165824, 25184256)     Mo
    //  [25184256, 25294848)     Wbf
    char* ws = (char*)d_ws;
    unsigned short* xt   = (unsigned short*)(ws);
    unsigned short* abuf = (unsigned short*)(ws);
    unsigned short* tbuf = (unsigned short*)(ws + 12582912);
    unsigned short* Mo   = (unsigned short*)(ws + 25165824);
    unsigned short* Wbf  = (unsigned short*)(ws + 25184256);
    float* out = (float*)d_out;

    prep_kernel<<<252, 256, 0, stream>>>(W1, W2, Wx, Wy, Mo, Wbf);
    hipMemsetAsync(xt, 0, 2*38*50*50*32*2, stream);      // zero halo for conv
    hipMemsetAsync(tbuf, 0, 12582912, stream);           // zero K-pad columns of t
    tx_kernel<<<3456, 256, 0, stream>>>(x, y, xt);
    conv_kernel<<<864, 256, 0, stream>>>(xt, bx, by, Wbf, tbuf);
    rt_kernel<<<256, 256, 0, stream>>>(tbuf, Mo, abuf);
    att_kernel<<<2048, 256, 0, stream>>>(abuf, out);
}

// Round 3
// 100.122 us; speedup vs baseline: 1.6650x; 1.2009x over previous
//
#include <hip/hip_runtime.h>
#include <hip/hip_bf16.h>

typedef __attribute__((ext_vector_type(8))) short short8;
typedef __attribute__((ext_vector_type(4))) float f32x4;

// ---- geometry ----
// x,y: (1,32,36,48,48) f32.  conv 3x3x3 SAME -> unfold P=9 -> t (32,1024,81)
// res_trans: a = LeakyReLU(t @ (W2@W1)^T)   (81x81 collapsed matrix M)
// att: (1/81) * a @ b^T per channel -> (1,32,1024,1024) f32
// K padded 81 -> 96 in t/a/b buffers.
//
// conv strategy: pre-transpose x,y into zero-padded ci-innermost bf16 layout
// xt[img][38][50][50][32]; conv then needs NO LDS -- every MFMA B fragment is
// a fully-coalesced contiguous 1KB global load (L1/L2 resident).
// All zero-fills are done inside setup_kernel (rocclr fillBuffer ran at only
// 155 GB/s for these sizes -- 2x ~80us dispatches in the round-2 profile).

static __device__ __forceinline__ unsigned short f2bf(float f) {
    unsigned int u = __float_as_uint(f);
    unsigned int r = (u + 0x7fffu + ((u >> 16) & 1u)) >> 16;
    return (unsigned short)r;
}

// ---------------- setup: transpose+pad, M=W2@W1, weight rearrange, t-pads ----
// blocks [0,3800)    : tx  (img,dd,hh) rows of xt, halo rows zeroed
// blocks [3800,3836) : M = W2@W1 -> bf16 96x96 (pad zeroed)
// blocks [3836,4052) : Wbf[img][tap(27)][co(32)][ci(32)]
// blocks [4052,4308) : zero pad columns 81..95 of tbuf rows
__global__ __launch_bounds__(256) void setup_kernel(
    const float* __restrict__ x, const float* __restrict__ y,
    const float* __restrict__ W1, const float* __restrict__ W2,
    const float* __restrict__ Wx, const float* __restrict__ Wy,
    unsigned short* __restrict__ xt, unsigned short* __restrict__ Mo,
    unsigned short* __restrict__ Wbf, unsigned short* __restrict__ tbuf) {
    int bb = blockIdx.x, tid = threadIdx.x;
    if (bb < 3800) {
        int img = bb / 1900, rr = bb % 1900;
        int dd = rr / 50, hh = rr % 50;
        unsigned short* dst = xt + img*(38*50*50*32) + (dd*50 + hh)*(50*32);
        if (dd >= 1 && dd <= 36 && hh >= 1 && hh <= 48) {
            __shared__ unsigned short lds[48*33];
            int d = dd - 1, h = hh - 1;
            const float* src = img ? y : x;
            #pragma unroll
            for (int i = 0; i < 6; ++i) {           // 1536 = 32ci x 48w reads
                int idx = tid + 256*i;
                int ci = idx / 48, w = idx % 48;
                lds[w*33 + ci] = f2bf(src[((ci*36 + d)*48 + h)*48 + w]);
            }
            __syncthreads();
            #pragma unroll
            for (int i = 0; i < 7; ++i) {           // 1600 = 50w' x 32ci writes
                int idx = tid + 256*i;
                if (idx < 1600) {
                    int wp = idx >> 5, ci = idx & 31;
                    unsigned short v = (wp == 0 || wp == 49) ? (unsigned short)0
                                                             : lds[(wp-1)*33 + ci];
                    dst[idx] = v;
                }
            }
        } else {
            #pragma unroll
            for (int i = 0; i < 7; ++i) {
                int idx = tid + 256*i;
                if (idx < 1600) dst[idx] = 0;
            }
        }
    } else if (bb < 3836) {
        int gid = (bb - 3800)*256 + tid;            // 9216 = 96*96
        int o = gid / 96, p = gid % 96;
        float v = 0.f;
        if (o < 81 && p < 81) {
            for (int k = 0; k < 162; ++k) v += W2[o*162 + k] * W1[k*81 + p];
        }
        Mo[o*96 + p] = f2bf(v);
    } else if (bb < 4052) {
        int e = (bb - 3836)*256 + tid;              // 2*27*32*32 = 55296
        if (e < 2*27*32*32) {
            int ci  = e % 32;
            int co  = (e / 32) % 32;
            int tap = (e / 1024) % 27;
            int img = e / 27648;
            const float* src = img ? Wy : Wx;
            Wbf[e] = f2bf(src[co*864 + ci*27 + tap]);
        }
    } else {
        int row = (bb - 4052)*256 + tid;            // 65536 rows of tbuf
        unsigned short* tr = tbuf + row*96 + 81;
        #pragma unroll
        for (int j = 0; j < 15; ++j) tr[j] = 0;
    }
}

// ---------------- conv (implicit GEMM, no LDS) -------------------------------
// block: one (img, d0, 4 h-rows); wave = one h-row, 3 w-tiles of 16, 2 co-tiles
__global__ __launch_bounds__(256) void conv_kernel(
    const unsigned short* __restrict__ xt,
    const float* __restrict__ bx, const float* __restrict__ by,
    const unsigned short* __restrict__ Wbf, unsigned short* __restrict__ tbuf) {
    int b = blockIdx.x;
    int img = b / 432; int rr = b % 432;
    int d0 = rr / 12; int h0 = (rr % 12) * 4;
    int tid = threadIdx.x, wv = tid >> 6, lane = tid & 63;
    int r16 = lane & 15, g4 = lane >> 4;
    const unsigned short* Ximg = xt + img*(38*50*50*32);
    const unsigned short* Wimg = Wbf + img*(27*32*32);
    const float* bias = img ? by : bx;

    f32x4 acc[2][3];
    #pragma unroll
    for (int i = 0; i < 2; ++i)
        #pragma unroll
        for (int j = 0; j < 3; ++j) acc[i][j] = (f32x4){0.f, 0.f, 0.f, 0.f};

    int hbase = h0 + wv;
    #pragma unroll
    for (int kd = 0; kd < 3; ++kd)
    #pragma unroll
    for (int kh = 0; kh < 3; ++kh) {
        const unsigned short* xrow = Ximg + ((d0 + kd)*50 + (hbase + kh))*50*32;
        #pragma unroll
        for (int kw = 0; kw < 3; ++kw) {
            int tap = (kd*3 + kh)*3 + kw;
            short8 a0 = *reinterpret_cast<const short8*>(Wimg + (tap*32 +      r16)*32 + 8*g4);
            short8 a1 = *reinterpret_cast<const short8*>(Wimg + (tap*32 + 16 + r16)*32 + 8*g4);
            #pragma unroll
            for (int wt = 0; wt < 3; ++wt) {
                short8 bfr = *reinterpret_cast<const short8*>(xrow + (wt*16 + r16 + kw)*32 + 8*g4);
                acc[0][wt] = __builtin_amdgcn_mfma_f32_16x16x32_bf16(a0, bfr, acc[0][wt], 0, 0, 0);
                acc[1][wt] = __builtin_amdgcn_mfma_f32_16x16x32_bf16(a1, bfr, acc[1][wt], 0, 0, 0);
            }
        }
    }

    // epilogue: + bias, write directly in unfolded layout (C,1024,96) bf16
    int h = hbase;
    int l_hi = (d0/9)*256, p_hi = (d0%9)*9;
    unsigned short* tb = tbuf + img*(32*1024*96);
    #pragma unroll
    for (int ct = 0; ct < 2; ++ct)
    #pragma unroll
    for (int wt = 0; wt < 3; ++wt)
    #pragma unroll
    for (int r = 0; r < 4; ++r) {
        int co = ct*16 + g4*4 + r;
        int w  = wt*16 + r16;
        float v = acc[ct][wt][r] + bias[co];
        int hw = h*48 + w;
        int l = l_hi + hw/9, p = p_hi + hw%9;
        tb[(co*1024 + l)*96 + p] = f2bf(v);
    }
}

// ---------------- res_trans: a = LeakyReLU(t @ M^T), per (img,c) -------------
__global__ __launch_bounds__(256) void rt_kernel(const unsigned short* __restrict__ tbuf,
                                                 const unsigned short* __restrict__ Mo,
                                                 unsigned short* __restrict__ ab) {
    int b = blockIdx.x;
    int img = b >> 7, c = (b >> 2) & 31, mc = b & 3;
    int tid = threadIdx.x, wv = tid >> 6, lane = tid & 63;
    int r16 = lane & 15, g4 = lane >> 4;

    short8 Bf[3][6];
    #pragma unroll
    for (int ks = 0; ks < 3; ++ks)
        #pragma unroll
        for (int n = 0; n < 6; ++n)
            Bf[ks][n] = *reinterpret_cast<const short8*>(Mo + (n*16 + r16)*96 + ks*32 + 8*g4);

    const unsigned short* tc = tbuf + (img*32 + c)*(1024*96);
    unsigned short*       oc = ab   + (img*32 + c)*(1024*96);
    for (int q = 0; q < 4; ++q) {
        int rowb = (mc*16 + wv*4 + q) * 16;
        f32x4 acc[6];
        #pragma unroll
        for (int n = 0; n < 6; ++n) acc[n] = (f32x4){0.f, 0.f, 0.f, 0.f};
        #pragma unroll
        for (int ks = 0; ks < 3; ++ks) {
            short8 Af = *reinterpret_cast<const short8*>(tc + (rowb + r16)*96 + ks*32 + 8*g4);
            #pragma unroll
            for (int n = 0; n < 6; ++n)
                acc[n] = __builtin_amdgcn_mfma_f32_16x16x32_bf16(Af, Bf[ks][n], acc[n], 0, 0, 0);
        }
        #pragma unroll
        for (int n = 0; n < 6; ++n)
            #pragma unroll
            for (int r = 0; r < 4; ++r) {
                int row = rowb + g4*4 + r;
                float v = acc[n][r];
                v = v > 0.f ? v : 0.2f*v;
                oc[row*96 + n*16 + r16] = f2bf(v);
            }
    }
}

// ---------------- att: out = (1/81) a @ b^T per channel ----------------------
__global__ __launch_bounds__(256) void att_kernel(const unsigned short* __restrict__ ab,
                                                  float* __restrict__ out) {
    int b = blockIdx.x;
    int c = b >> 6, ty = (b >> 3) & 7, tx = b & 7;
    int tid = threadIdx.x, wv = tid >> 6, lane = tid & 63;
    int r16 = lane & 15, g4 = lane >> 4;
    const unsigned short* arow = ab + c*(1024*96);
    const unsigned short* brow = ab + (32 + c)*(1024*96);
    int rb = ty*128 + wv*32;
    int cb = tx*128;
    f32x4 acc[2][8];
    #pragma unroll
    for (int m = 0; m < 2; ++m)
        #pragma unroll
        for (int n = 0; n < 8; ++n) acc[m][n] = (f32x4){0.f, 0.f, 0.f, 0.f};

    #pragma unroll
    for (int ks = 0; ks < 3; ++ks) {
        short8 A0 = *reinterpret_cast<const short8*>(arow + (rb +      r16)*96 + ks*32 + 8*g4);
        short8 A1 = *reinterpret_cast<const short8*>(arow + (rb + 16 + r16)*96 + ks*32 + 8*g4);
        #pragma unroll
        for (int n = 0; n < 8; ++n) {
            short8 Bf = *reinterpret_cast<const short8*>(brow + (cb + n*16 + r16)*96 + ks*32 + 8*g4);
            acc[0][n] = __builtin_amdgcn_mfma_f32_16x16x32_bf16(A0, Bf, acc[0][n], 0, 0, 0);
            acc[1][n] = __builtin_amdgcn_mfma_f32_16x16x32_bf16(A1, Bf, acc[1][n], 0, 0, 0);
        }
    }
    const float s = 1.f / 81.f;
    #pragma unroll
    for (int mt = 0; mt < 2; ++mt)
        #pragma unroll
        for (int n = 0; n < 8; ++n)
            #pragma unroll
            for (int r = 0; r < 4; ++r) {
                int row = rb + mt*16 + g4*4 + r;
                int col = cb + n*16 + r16;
                out[(c*1024 + row)*1024 + col] = acc[mt][n][r] * s;
            }
}

extern "C" void kernel_launch(void* const* d_in, const int* in_sizes, int n_in,
                              void* d_out, int out_size, void* d_ws, size_t ws_size,
                              hipStream_t stream) {
    const float* x  = (const float*)d_in[0];
    const float* y  = (const float*)d_in[1];
    const float* Wx = (const float*)d_in[2];
    const float* bx = (const float*)d_in[3];
    const float* Wy = (const float*)d_in[4];
    const float* by = (const float*)d_in[5];
    const float* W1 = (const float*)d_in[6];
    const float* W2 = (const float*)d_in[7];
    (void)in_sizes; (void)n_in; (void)out_size; (void)ws_size;

    // workspace plan (total 25.30 MB):
    //  [0, 12582912)            xt (12.16 MB, dead after conv) then abuf (12.58 MB)
    //  [12582912, 25165824)     tbuf (12.58 MB)
    //  [25165824, 25184256)     Mo
    //  [25184256, 25294848)     Wbf
    char* ws = (char*)d_ws;
    unsigned short* xt   = (unsigned short*)(ws);
    unsigned short* abuf = (unsigned short*)(ws);
    unsigned short* tbuf = (unsigned short*)(ws + 12582912);
    unsigned short* Mo   = (unsigned short*)(ws + 25165824);
    unsigned short* Wbf  = (unsigned short*)(ws + 25184256);
    float* out = (float*)d_out;

    setup_kernel<<<4308, 256, 0, stream>>>(x, y, W1, W2, Wx, Wy, xt, Mo, Wbf, tbuf);
    conv_kernel<<<864, 256, 0, stream>>>(xt, bx, by, Wbf, tbuf);
    rt_kernel<<<256, 256, 0, stream>>>(tbuf, Mo, abuf);
    att_kernel<<<2048, 256, 0, stream>>>(abuf, out);
}

// Round 4
// 86.795 us; speedup vs baseline: 1.9207x; 1.1536x over previous
//
#include <hip/hip_runtime.h>
#include <hip/hip_bf16.h>

typedef __attribute__((ext_vector_type(8))) short short8;
typedef __attribute__((ext_vector_type(4))) float f32x4;

// ---- geometry ----
// x,y: (1,32,36,48,48) f32.  conv 3x3x3 SAME -> unfold P=9 -> t (32,1024,81)
// res_trans: a = LeakyReLU(t @ (W2@W1)^T)   (81x81 collapsed matrix M)
// att: (1/81) * a @ b^T per channel -> (1,32,1024,1024) f32
// K padded 81 -> 96 in t/a/b buffers.
//
// conv: pre-transposed zero-padded ci-innermost bf16 layout xt[img][38][50][50][32];
// no LDS -- every MFMA B fragment is a coalesced contiguous 1KB global load.
// Each wave computes 2 adjacent h-rows (x-fragment reuse across kh windows) and
// per-kd weight fragments are hoisted into registers (loaded once, used 12x).

static __device__ __forceinline__ unsigned short f2bf(float f) {
    unsigned int u = __float_as_uint(f);
    unsigned int r = (u + 0x7fffu + ((u >> 16) & 1u)) >> 16;
    return (unsigned short)r;
}

// ---------------- setup: transpose+pad, M=W2@W1, weight rearrange, t-pads ----
// blocks [0,3800)    : tx  (img,dd,hh) rows of xt, halo rows zeroed
// blocks [3800,3836) : M = W2@W1 -> bf16 96x96 (pad zeroed)
// blocks [3836,4052) : Wbf[img][tap(27)][co(32)][ci(32)]
// blocks [4052,4308) : zero pad columns 81..95 of tbuf rows
__global__ __launch_bounds__(256) void setup_kernel(
    const float* __restrict__ x, const float* __restrict__ y,
    const float* __restrict__ W1, const float* __restrict__ W2,
    const float* __restrict__ Wx, const float* __restrict__ Wy,
    unsigned short* __restrict__ xt, unsigned short* __restrict__ Mo,
    unsigned short* __restrict__ Wbf, unsigned short* __restrict__ tbuf) {
    int bb = blockIdx.x, tid = threadIdx.x;
    if (bb < 3800) {
        int img = bb / 1900, rr = bb % 1900;
        int dd = rr / 50, hh = rr % 50;
        unsigned short* dst = xt + img*(38*50*50*32) + (dd*50 + hh)*(50*32);
        if (dd >= 1 && dd <= 36 && hh >= 1 && hh <= 48) {
            __shared__ unsigned short lds[48*33];
            int d = dd - 1, h = hh - 1;
            const float* src = img ? y : x;
            #pragma unroll
            for (int i = 0; i < 6; ++i) {           // 1536 = 32ci x 48w reads
                int idx = tid + 256*i;
                int ci = idx / 48, w = idx % 48;
                lds[w*33 + ci] = f2bf(src[((ci*36 + d)*48 + h)*48 + w]);
            }
            __syncthreads();
            #pragma unroll
            for (int i = 0; i < 7; ++i) {           // 1600 = 50w' x 32ci writes
                int idx = tid + 256*i;
                if (idx < 1600) {
                    int wp = idx >> 5, ci = idx & 31;
                    unsigned short v = (wp == 0 || wp == 49) ? (unsigned short)0
                                                             : lds[(wp-1)*33 + ci];
                    dst[idx] = v;
                }
            }
        } else {
            #pragma unroll
            for (int i = 0; i < 7; ++i) {
                int idx = tid + 256*i;
                if (idx < 1600) dst[idx] = 0;
            }
        }
    } else if (bb < 3836) {
        int gid = (bb - 3800)*256 + tid;            // 9216 = 96*96
        int o = gid / 96, p = gid % 96;
        float v = 0.f;
        if (o < 81 && p < 81) {
            for (int k = 0; k < 162; ++k) v += W2[o*162 + k] * W1[k*81 + p];
        }
        Mo[o*96 + p] = f2bf(v);
    } else if (bb < 4052) {
        int e = (bb - 3836)*256 + tid;              // 2*27*32*32 = 55296
        if (e < 2*27*32*32) {
            int ci  = e % 32;
            int co  = (e / 32) % 32;
            int tap = (e / 1024) % 27;
            int img = e / 27648;
            const float* src = img ? Wy : Wx;
            Wbf[e] = f2bf(src[co*864 + ci*27 + tap]);
        }
    } else {
        int row = (bb - 4052)*256 + tid;            // 65536 rows of tbuf
        unsigned short* tr = tbuf + row*96 + 81;
        #pragma unroll
        for (int j = 0; j < 15; ++j) tr[j] = 0;
    }
}

// ---------------- conv (implicit GEMM, no LDS, 2 h-rows/wave) ----------------
// grid 432 = img(2) x d(36) x hblk(6); wave wv covers h rows hblk*8+2wv+{0,1}
__global__ __launch_bounds__(256) void conv_kernel(
    const unsigned short* __restrict__ xt,
    const float* __restrict__ bx, const float* __restrict__ by,
    const unsigned short* __restrict__ Wbf, unsigned short* __restrict__ tbuf) {
    int b = blockIdx.x;
    int img = b / 216; int rr = b % 216;
    int d0 = rr / 6; int hb = rr % 6;
    int tid = threadIdx.x, wv = tid >> 6, lane = tid & 63;
    int r16 = lane & 15, g4 = lane >> 4;
    int hbase = hb*8 + wv*2;
    const unsigned short* Ximg = xt + img*(38*50*50*32);
    const unsigned short* Wimg = Wbf + img*(27*32*32);
    const float* bias = img ? by : bx;

    f32x4 acc[2][3][2];                  // [co-tile][w-tile][hh]
    #pragma unroll
    for (int i = 0; i < 2; ++i)
        #pragma unroll
        for (int j = 0; j < 3; ++j)
            #pragma unroll
            for (int k = 0; k < 2; ++k) acc[i][j][k] = (f32x4){0.f, 0.f, 0.f, 0.f};

    #pragma unroll 1
    for (int kd = 0; kd < 3; ++kd) {
        // hoist this kd-plane's 18 weight fragments into registers
        short8 wf[3][3][2];
        #pragma unroll
        for (int kh = 0; kh < 3; ++kh)
            #pragma unroll
            for (int kw = 0; kw < 3; ++kw)
                #pragma unroll
                for (int ct = 0; ct < 2; ++ct)
                    wf[kh][kw][ct] = *reinterpret_cast<const short8*>(
                        Wimg + (((kd*3 + kh)*3 + kw)*32 + ct*16 + r16)*32 + 8*g4);
        #pragma unroll
        for (int r = 0; r < 4; ++r) {    // xt rows hbase+0..hbase+3 (halo incl.)
            const unsigned short* xrow = Ximg + ((d0 + kd)*50 + (hbase + r))*(50*32);
            #pragma unroll
            for (int kw = 0; kw < 3; ++kw) {
                short8 bfr[3];
                #pragma unroll
                for (int wt = 0; wt < 3; ++wt)
                    bfr[wt] = *reinterpret_cast<const short8*>(xrow + (wt*16 + r16 + kw)*32 + 8*g4);
                #pragma unroll
                for (int hh = 0; hh < 2; ++hh) {
                    int kh = r - hh;
                    if (kh >= 0 && kh < 3) {
                        #pragma unroll
                        for (int wt = 0; wt < 3; ++wt) {
                            acc[0][wt][hh] = __builtin_amdgcn_mfma_f32_16x16x32_bf16(wf[kh][kw][0], bfr[wt], acc[0][wt][hh], 0, 0, 0);
                            acc[1][wt][hh] = __builtin_amdgcn_mfma_f32_16x16x32_bf16(wf[kh][kw][1], bfr[wt], acc[1][wt][hh], 0, 0, 0);
                        }
                    }
                }
            }
        }
    }

    // epilogue: + bias, write directly in unfolded layout (C,1024,96) bf16
    int l_hi = (d0/9)*256, p_hi = (d0%9)*9;
    unsigned short* tb = tbuf + img*(32*1024*96);
    #pragma unroll
    for (int hh = 0; hh < 2; ++hh) {
        int h = hbase + hh;
        #pragma unroll
        for (int ct = 0; ct < 2; ++ct)
            #pragma unroll
            for (int wt = 0; wt < 3; ++wt)
                #pragma unroll
                for (int r = 0; r < 4; ++r) {
                    int co = ct*16 + g4*4 + r;
                    int w  = wt*16 + r16;
                    float v = acc[ct][wt][hh][r] + bias[co];
                    int hw = h*48 + w;
                    int l = l_hi + hw/9, p = p_hi + hw%9;
                    tb[(co*1024 + l)*96 + p] = f2bf(v);
                }
    }
}

// ---------------- res_trans: a = LeakyReLU(t @ M^T), per (img,c) -------------
__global__ __launch_bounds__(256) void rt_kernel(const unsigned short* __restrict__ tbuf,
                                                 const unsigned short* __restrict__ Mo,
                                                 unsigned short* __restrict__ ab) {
    int b = blockIdx.x;
    int img = b >> 7, c = (b >> 2) & 31, mc = b & 3;
    int tid = threadIdx.x, wv = tid >> 6, lane = tid & 63;
    int r16 = lane & 15, g4 = lane >> 4;

    short8 Bf[3][6];
    #pragma unroll
    for (int ks = 0; ks < 3; ++ks)
        #pragma unroll
        for (int n = 0; n < 6; ++n)
            Bf[ks][n] = *reinterpret_cast<const short8*>(Mo + (n*16 + r16)*96 + ks*32 + 8*g4);

    const unsigned short* tc = tbuf + (img*32 + c)*(1024*96);
    unsigned short*       oc = ab   + (img*32 + c)*(1024*96);
    for (int q = 0; q < 4; ++q) {
        int rowb = (mc*16 + wv*4 + q) * 16;
        f32x4 acc[6];
        #pragma unroll
        for (int n = 0; n < 6; ++n) acc[n] = (f32x4){0.f, 0.f, 0.f, 0.f};
        #pragma unroll
        for (int ks = 0; ks < 3; ++ks) {
            short8 Af = *reinterpret_cast<const short8*>(tc + (rowb + r16)*96 + ks*32 + 8*g4);
            #pragma unroll
            for (int n = 0; n < 6; ++n)
                acc[n] = __builtin_amdgcn_mfma_f32_16x16x32_bf16(Af, Bf[ks][n], acc[n], 0, 0, 0);
        }
        #pragma unroll
        for (int n = 0; n < 6; ++n)
            #pragma unroll
            for (int r = 0; r < 4; ++r) {
                int row = rowb + g4*4 + r;
                float v = acc[n][r];
                v = v > 0.f ? v : 0.2f*v;
                oc[row*96 + n*16 + r16] = f2bf(v);
            }
    }
}

// ---------------- att: out = (1/81) a @ b^T per channel ----------------------
// XCD-swizzled so all 64 tiles of one channel share an XCD's L2 (a+b = 392 KB)
__global__ __launch_bounds__(256) void att_kernel(const unsigned short* __restrict__ ab,
                                                  float* __restrict__ out) {
    int bid = blockIdx.x;
    int b = (bid & 7) * 256 + (bid >> 3);   // bijective: 2048 = 8 * 256
    int c = b >> 6, ty = (b >> 3) & 7, tx = b & 7;
    int tid = threadIdx.x, wv = tid >> 6, lane = tid & 63;
    int r16 = lane & 15, g4 = lane >> 4;
    const unsigned short* arow = ab + c*(1024*96);
    const unsigned short* brow = ab + (32 + c)*(1024*96);
    int rb = ty*128 + wv*32;
    int cb = tx*128;
    f32x4 acc[2][8];
    #pragma unroll
    for (int m = 0; m < 2; ++m)
        #pragma unroll
        for (int n = 0; n < 8; ++n) acc[m][n] = (f32x4){0.f, 0.f, 0.f, 0.f};

    #pragma unroll
    for (int ks = 0; ks < 3; ++ks) {
        short8 A0 = *reinterpret_cast<const short8*>(arow + (rb +      r16)*96 + ks*32 + 8*g4);
        short8 A1 = *reinterpret_cast<const short8*>(arow + (rb + 16 + r16)*96 + ks*32 + 8*g4);
        #pragma unroll
        for (int n = 0; n < 8; ++n) {
            short8 Bf = *reinterpret_cast<const short8*>(brow + (cb + n*16 + r16)*96 + ks*32 + 8*g4);
            acc[0][n] = __builtin_amdgcn_mfma_f32_16x16x32_bf16(A0, Bf, acc[0][n], 0, 0, 0);
            acc[1][n] = __builtin_amdgcn_mfma_f32_16x16x32_bf16(A1, Bf, acc[1][n], 0, 0, 0);
        }
    }
    const float s = 1.f / 81.f;
    #pragma unroll
    for (int mt = 0; mt < 2; ++mt)
        #pragma unroll
        for (int n = 0; n < 8; ++n)
            #pragma unroll
            for (int r = 0; r < 4; ++r) {
                int row = rb + mt*16 + g4*4 + r;
                int col = cb + n*16 + r16;
                out[(c*1024 + row)*1024 + col] = acc[mt][n][r] * s;
            }
}

extern "C" void kernel_launch(void* const* d_in, const int* in_sizes, int n_in,
                              void* d_out, int out_size, void* d_ws, size_t ws_size,
                              hipStream_t stream) {
    const float* x  = (const float*)d_in[0];
    const float* y  = (const float*)d_in[1];
    const float* Wx = (const float*)d_in[2];
    const float* bx = (const float*)d_in[3];
    const float* Wy = (const float*)d_in[4];
    const float* by = (const float*)d_in[5];
    const float* W1 = (const float*)d_in[6];
    const float* W2 = (const float*)d_in[7];
    (void)in_sizes; (void)n_in; (void)out_size; (void)ws_size;

    // workspace plan (total 25.30 MB):
    //  [0, 12582912)            xt (12.16 MB, dead after conv) then abuf (12.58 MB)
    //  [12582912, 25165824)     tbuf (12.58 MB)
    //  [25165824, 25184256)     Mo
    //  [25184256, 25294848)     Wbf
    char* ws = (char*)d_ws;
    unsigned short* xt   = (unsigned short*)(ws);
    unsigned short* abuf = (unsigned short*)(ws);
    unsigned short* tbuf = (unsigned short*)(ws + 12582912);
    unsigned short* Mo   = (unsigned short*)(ws + 25165824);
    unsigned short* Wbf  = (unsigned short*)(ws + 25184256);
    float* out = (float*)d_out;

    setup_kernel<<<4308, 256, 0, stream>>>(x, y, W1, W2, Wx, Wy, xt, Mo, Wbf, tbuf);
    conv_kernel<<<432, 256, 0, stream>>>(xt, bx, by, Wbf, tbuf);
    rt_kernel<<<256, 256, 0, stream>>>(tbuf, Mo, abuf);
    att_kernel<<<2048, 256, 0, stream>>>(abuf, out);
}